// Round 1
// baseline (135.003 us; speedup 1.0000x reference)
//
#include <hip/hip_runtime.h>

// Problem constants
#define B_   8
#define TE_  256
#define TD_  256
#define D_   256
#define U_   256

// Workspace layout (float offsets). Total 1,576,960 floats = 6.02 MB.
#define AE_OFF    0        // (B*TE, U)  en@w_en, pre-scaled by 2*log2(e)
#define AD_OFF    524288   // (B*TD, U)  de@w_de, pre-scaled by 2*log2(e)
#define MU_OFF    1048576  // (B, TD, TE) mu' -> overwritten in-place with alphas
#define MAXMU_OFF 1572864  // (B, TD)    row max of mu'
#define HH_OFF    1574912  // (B, D)     h_hat

__device__ __forceinline__ float fexp2(float x) {
#if __has_builtin(__builtin_amdgcn_exp2f)
  return __builtin_amdgcn_exp2f(x);
#else
  return exp2f(x);
#endif
}
__device__ __forceinline__ float frcp(float x) {
#if __has_builtin(__builtin_amdgcn_rcpf)
  return __builtin_amdgcn_rcpf(x);
#else
  return 1.0f / x;
#endif
}

#define LOG2E_F 1.4426950408889634f
#define TWO_LOG2E_F 2.8853900817779268f

// ---------------------------------------------------------------------------
// K1: ae' = (en @ w_en) * 2log2e ; ad' = (de @ w_de) * 2log2e
// Classic 64x64 tile, 4x4 microtile, KT=16 chunks. grid (4, 32, 2).
// ---------------------------------------------------------------------------
__global__ __launch_bounds__(256) void coatt_k1_proj(
    const float* __restrict__ en, const float* __restrict__ de,
    const float* __restrict__ w_en, const float* __restrict__ w_de,
    float* __restrict__ ws) {
  const int which = blockIdx.z;
  const float* __restrict__ A = which ? de : en;     // (2048, 256)
  const float* __restrict__ W = which ? w_de : w_en; // (256, 256)
  float* __restrict__ out = ws + (which ? AD_OFF : AE_OFF);
  const int rowBase = blockIdx.y * 64;
  const int colBase = blockIdx.x * 64;
  __shared__ float As[16][68];  // A^T chunk: As[k][row], pad 68 (16B-aligned rows, 2-way max)
  __shared__ float Bs[16][68];  // Bs[k][col]
  const int tid = threadIdx.x;
  const int tx = tid & 15, ty = tid >> 4;
  float acc[4][4] = {};
  for (int k0 = 0; k0 < D_; k0 += 16) {
    {
      const int r = tid >> 2;          // 0..63
      const int c = (tid & 3) * 4;     // 0,4,8,12
      const float4 a4 = *(const float4*)&A[(rowBase + r) * D_ + k0 + c];
      As[c + 0][r] = a4.x; As[c + 1][r] = a4.y;
      As[c + 2][r] = a4.z; As[c + 3][r] = a4.w;
      const int kk = tid >> 4;         // 0..15
      const int cc = (tid & 15) * 4;   // 0..60
      *(float4*)&Bs[kk][cc] = *(const float4*)&W[(k0 + kk) * U_ + colBase + cc];
    }
    __syncthreads();
#pragma unroll
    for (int k = 0; k < 16; ++k) {
      float av[4], bv[4];
      *(float4*)av = *(const float4*)&As[k][ty * 4];
      *(float4*)bv = *(const float4*)&Bs[k][tx * 4];
#pragma unroll
      for (int i = 0; i < 4; ++i)
#pragma unroll
        for (int j = 0; j < 4; ++j)
          acc[i][j] = fmaf(av[i], bv[j], acc[i][j]);
    }
    __syncthreads();
  }
#pragma unroll
  for (int i = 0; i < 4; ++i) {
    float4 o;
    o.x = acc[i][0] * TWO_LOG2E_F; o.y = acc[i][1] * TWO_LOG2E_F;
    o.z = acc[i][2] * TWO_LOG2E_F; o.w = acc[i][3] * TWO_LOG2E_F;
    *(float4*)&out[(rowBase + ty * 4 + i) * U_ + colBase + tx * 4] = o;
  }
}

// ---------------------------------------------------------------------------
// K2 (dominant): mu'[b,s,t] = sum_u (-2 nu_u) / (exp2(ad'[b,s,u]+ae'[b,t,u]) + 1)
//   (= sum_u nu_u * tanh(ad+ae) minus the global constant sum(nu) — softmax-invariant)
// 32x32 (s,t) tile per block, 2x2 per thread (strided +16), u-chunks of 16.
// grid (8, 8, 8) = 512 blocks.
// ---------------------------------------------------------------------------
__global__ __launch_bounds__(256) void coatt_k2_mu(
    const float* __restrict__ nu, float* __restrict__ ws) {
  const float* __restrict__ ae = ws + AE_OFF;
  const float* __restrict__ ad = ws + AD_OFF;
  float* __restrict__ mu = ws + MU_OFF;
  const int b = blockIdx.z;
  const int sBase = blockIdx.y * 32;
  const int tBase = blockIdx.x * 32;
  __shared__ float ADs[32][20];  // pad 20: rows 80B (16B-aligned), conflict-free b128 reads
  __shared__ float AEs[32][20];
  __shared__ float NUs[16];
  const int tid = threadIdx.x;
  const int tx = tid & 15;
  const int sy = tid >> 4;
  float acc00 = 0.f, acc01 = 0.f, acc10 = 0.f, acc11 = 0.f;
  for (int u0 = 0; u0 < U_; u0 += 16) {
    {
      const int r = (tid & 127) >> 2;  // 0..31
      const int c = (tid & 3) * 4;
      if (tid < 128)
        *(float4*)&ADs[r][c] = *(const float4*)&ad[(b * TD_ + sBase + r) * U_ + u0 + c];
      else
        *(float4*)&AEs[r][c] = *(const float4*)&ae[(b * TE_ + tBase + r) * U_ + u0 + c];
      if (tid < 4) {
        const float4 n4 = *(const float4*)&nu[u0 + tid * 4];
        NUs[tid * 4 + 0] = -2.0f * n4.x;
        NUs[tid * 4 + 1] = -2.0f * n4.y;
        NUs[tid * 4 + 2] = -2.0f * n4.z;
        NUs[tid * 4 + 3] = -2.0f * n4.w;
      }
    }
    __syncthreads();
    const float4* A0 = (const float4*)&ADs[sy][0];
    const float4* A1 = (const float4*)&ADs[sy + 16][0];
    const float4* E0 = (const float4*)&AEs[tx][0];
    const float4* E1 = (const float4*)&AEs[tx + 16][0];
    const float4* N4 = (const float4*)&NUs[0];
#pragma unroll
    for (int q = 0; q < 4; ++q) {
      float a0v[4], a1v[4], e0v[4], e1v[4], nv[4];
      *(float4*)a0v = A0[q];
      *(float4*)a1v = A1[q];
      *(float4*)e0v = E0[q];
      *(float4*)e1v = E1[q];
      *(float4*)nv  = N4[q];
#pragma unroll
      for (int u = 0; u < 4; ++u) {
        const float r00 = frcp(fexp2(a0v[u] + e0v[u]) + 1.0f);
        const float r01 = frcp(fexp2(a0v[u] + e1v[u]) + 1.0f);
        const float r10 = frcp(fexp2(a1v[u] + e0v[u]) + 1.0f);
        const float r11 = frcp(fexp2(a1v[u] + e1v[u]) + 1.0f);
        acc00 = fmaf(nv[u], r00, acc00);
        acc01 = fmaf(nv[u], r01, acc01);
        acc10 = fmaf(nv[u], r10, acc10);
        acc11 = fmaf(nv[u], r11, acc11);
      }
    }
    __syncthreads();
  }
  const int s0 = sBase + sy, s1 = s0 + 16;
  const int t0 = tBase + tx, t1 = t0 + 16;
  mu[(b * TD_ + s0) * TE_ + t0] = acc00;
  mu[(b * TD_ + s0) * TE_ + t1] = acc01;
  mu[(b * TD_ + s1) * TE_ + t0] = acc10;
  mu[(b * TD_ + s1) * TE_ + t1] = acc11;
}

// ---------------------------------------------------------------------------
// K3: per-(b,s) row softmax over te (in-place mu -> alphas) + row max out.
// grid 2048 blocks x 256 threads.
// ---------------------------------------------------------------------------
__global__ __launch_bounds__(256) void coatt_k3_softmax(float* __restrict__ ws) {
  float* __restrict__ mu = ws + MU_OFF;
  float* __restrict__ maxmu = ws + MAXMU_OFF;
  const int row = blockIdx.x;  // b*TD + s
  const int tid = threadIdx.x;
  __shared__ float red[256];
  const float v = mu[row * TE_ + tid];
  red[tid] = v;
  __syncthreads();
  for (int w = 128; w > 0; w >>= 1) {
    if (tid < w) red[tid] = fmaxf(red[tid], red[tid + w]);
    __syncthreads();
  }
  const float m = red[0];
  __syncthreads();
  const float e = fexp2((v - m) * LOG2E_F);
  red[tid] = e;
  __syncthreads();
  for (int w = 128; w > 0; w >>= 1) {
    if (tid < w) red[tid] += red[tid + w];
    __syncthreads();
  }
  const float inv = frcp(red[0]);
  mu[row * TE_ + tid] = e * inv;
  if (tid == 0) maxmu[row] = m;
}

// ---------------------------------------------------------------------------
// K4: max_alphas = softmax_s(maxmu[b,:]) (recomputed per block, cheap);
//     h_hat[b,d] = sum_s de[b,s,d]*max_alphas[s].
// grid (8 dChunks, 8 b); each block covers 32 d, splits s 8 ways, LDS-reduces.
// ---------------------------------------------------------------------------
__global__ __launch_bounds__(256) void coatt_k4_hhat(
    const float* __restrict__ de, float* __restrict__ ws) {
  const float* __restrict__ maxmu = ws + MAXMU_OFF;
  float* __restrict__ hhat = ws + HH_OFF;
  const int b = blockIdx.y;
  const int dBase = blockIdx.x * 32;
  const int tid = threadIdx.x;
  __shared__ float red[256];
  __shared__ float malpha[256];
  const float v = maxmu[b * TD_ + tid];
  red[tid] = v;
  __syncthreads();
  for (int w = 128; w > 0; w >>= 1) {
    if (tid < w) red[tid] = fmaxf(red[tid], red[tid + w]);
    __syncthreads();
  }
  const float m = red[0];
  __syncthreads();
  const float e = fexp2((v - m) * LOG2E_F);
  red[tid] = e;
  __syncthreads();
  for (int w = 128; w > 0; w >>= 1) {
    if (tid < w) red[tid] += red[tid + w];
    __syncthreads();
  }
  malpha[tid] = e * frcp(red[0]);
  __syncthreads();
  const int dl = tid & 31, sg = tid >> 5;
  float acc = 0.f;
  for (int s = sg * 32; s < sg * 32 + 32; ++s)
    acc = fmaf(de[(b * TD_ + s) * D_ + dBase + dl], malpha[s], acc);
  red[tid] = acc;
  __syncthreads();
  if (tid < 32) {
    float t = red[tid];
#pragma unroll
    for (int g = 1; g < 8; ++g) t += red[g * 32 + tid];
    hhat[b * D_ + dBase + tid] = t;
  }
}

// ---------------------------------------------------------------------------
// K5: sum_en = alphas @ en (per-b 256x256 @ 256x256), fused with output concat:
//     out = [de | sum_en | de*sum_en | de*h_hat].  32x32 tile, 2x2/thread.
// grid (8 eTiles, 8 sTiles, 8 b) = 512 blocks.
// ---------------------------------------------------------------------------
__global__ __launch_bounds__(256) void coatt_k5_out(
    const float* __restrict__ en, const float* __restrict__ de,
    const float* __restrict__ ws, float* __restrict__ out) {
  const float* __restrict__ alphas = ws + MU_OFF;  // (B*TD, TE)
  const float* __restrict__ hhat = ws + HH_OFF;
  const int b = blockIdx.z;
  const int sBase = blockIdx.y * 32;
  const int eBase = blockIdx.x * 32;
  __shared__ float As[16][36];  // As[t][s] (alphas^T chunk), pad 36
  __shared__ float Bs[16][36];  // Bs[t][e]
  const int tid = threadIdx.x;
  const int tx = tid & 15, sy = tid >> 4;
  float acc[2][2] = {};
  for (int k0 = 0; k0 < TE_; k0 += 16) {
    if (tid < 128) {
      const int r = tid >> 2, c = (tid & 3) * 4;  // r: s-local, c: t-offset
      const float4 a4 = *(const float4*)&alphas[(b * TD_ + sBase + r) * TE_ + k0 + c];
      As[c + 0][r] = a4.x; As[c + 1][r] = a4.y;
      As[c + 2][r] = a4.z; As[c + 3][r] = a4.w;
    } else {
      const int id = tid & 127;
      const int kk = id >> 3, cc = (id & 7) * 4;  // kk: t-local, cc: e-offset
      *(float4*)&Bs[kk][cc] = *(const float4*)&en[(b * TE_ + k0 + kk) * D_ + eBase + cc];
    }
    __syncthreads();
#pragma unroll
    for (int k = 0; k < 16; ++k) {
      const float2 a2 = *(const float2*)&As[k][sy * 2];
      const float2 b2 = *(const float2*)&Bs[k][tx * 2];
      acc[0][0] = fmaf(a2.x, b2.x, acc[0][0]);
      acc[0][1] = fmaf(a2.x, b2.y, acc[0][1]);
      acc[1][0] = fmaf(a2.y, b2.x, acc[1][0]);
      acc[1][1] = fmaf(a2.y, b2.y, acc[1][1]);
    }
    __syncthreads();
  }
  const int e0 = eBase + tx * 2;
  const float2 hh = *(const float2*)&hhat[b * D_ + e0];
#pragma unroll
  for (int i = 0; i < 2; ++i) {
    const int s = sBase + sy * 2 + i;
    const float2 d2 = *(const float2*)&de[(b * TD_ + s) * D_ + e0];
    float* o = out + (size_t)(b * TD_ + s) * (4 * D_);
    float2 se; se.x = acc[i][0]; se.y = acc[i][1];
    *(float2*)&o[e0] = d2;
    *(float2*)&o[D_ + e0] = se;
    float2 p; p.x = d2.x * se.x; p.y = d2.y * se.y;
    *(float2*)&o[2 * D_ + e0] = p;
    float2 q; q.x = d2.x * hh.x; q.y = d2.y * hh.y;
    *(float2*)&o[3 * D_ + e0] = q;
  }
}

extern "C" void kernel_launch(void* const* d_in, const int* in_sizes, int n_in,
                              void* d_out, int out_size, void* d_ws, size_t ws_size,
                              hipStream_t stream) {
  (void)in_sizes; (void)n_in; (void)out_size; (void)ws_size;
  const float* en   = (const float*)d_in[0];
  const float* de   = (const float*)d_in[1];
  const float* w_en = (const float*)d_in[2];
  const float* w_de = (const float*)d_in[3];
  const float* nu   = (const float*)d_in[4];
  float* out = (float*)d_out;
  float* ws  = (float*)d_ws;

  coatt_k1_proj<<<dim3(4, 32, 2), 256, 0, stream>>>(en, de, w_en, w_de, ws);
  coatt_k2_mu<<<dim3(8, 8, 8), 256, 0, stream>>>(nu, ws);
  coatt_k3_softmax<<<dim3(2048), 256, 0, stream>>>(ws);
  coatt_k4_hhat<<<dim3(8, 8), 256, 0, stream>>>(de, ws);
  coatt_k5_out<<<dim3(8, 8, 8), 256, 0, stream>>>(en, de, ws, out);
}

// Round 2
// 122.628 us; speedup vs baseline: 1.1009x; 1.1009x over previous
//
#include <hip/hip_runtime.h>

// Problem constants
#define B_   8
#define TE_  256
#define TD_  256
#define D_   256
#define U_   256

// Workspace layout (float offsets). Total 1,576,960 floats = 6.02 MB.
#define AE_OFF    0        // (B*TE, U)  Ee = exp2(2*log2e * en@w_en)
#define AD_OFF    524288   // (B*TD, U)  Ed = exp2(2*log2e * de@w_de)
#define MU_OFF    1048576  // (B, TD, TE) mu' -> overwritten in-place with alphas
#define MAXMU_OFF 1572864  // (B, TD)    row max of mu'
#define HH_OFF    1574912  // (B, D)     h_hat

__device__ __forceinline__ float fexp2(float x) {
#if __has_builtin(__builtin_amdgcn_exp2f)
  return __builtin_amdgcn_exp2f(x);
#else
  return exp2f(x);
#endif
}
__device__ __forceinline__ float frcp(float x) {
#if __has_builtin(__builtin_amdgcn_rcpf)
  return __builtin_amdgcn_rcpf(x);
#else
  return 1.0f / x;
#endif
}

#define LOG2E_F 1.4426950408889634f
#define TWO_LOG2E_F 2.8853900817779268f

// ---------------------------------------------------------------------------
// K1: Ee = exp2((en @ w_en) * 2log2e) ; Ed = exp2((de @ w_de) * 2log2e)
// tanh(ad+ae) = 1 - 2/(Ed*Ee+1) -- exp factorization kills 134M exps in K2.
// Classic 64x64 tile, 4x4 microtile, KT=16 chunks. grid (4, 32, 2).
// ---------------------------------------------------------------------------
__global__ __launch_bounds__(256) void coatt_k1_proj(
    const float* __restrict__ en, const float* __restrict__ de,
    const float* __restrict__ w_en, const float* __restrict__ w_de,
    float* __restrict__ ws) {
  const int which = blockIdx.z;
  const float* __restrict__ A = which ? de : en;     // (2048, 256)
  const float* __restrict__ W = which ? w_de : w_en; // (256, 256)
  float* __restrict__ out = ws + (which ? AD_OFF : AE_OFF);
  const int rowBase = blockIdx.y * 64;
  const int colBase = blockIdx.x * 64;
  __shared__ float As[16][68];  // A^T chunk: As[k][row]
  __shared__ float Bs[16][68];  // Bs[k][col]
  const int tid = threadIdx.x;
  const int tx = tid & 15, ty = tid >> 4;
  float acc[4][4] = {};
  for (int k0 = 0; k0 < D_; k0 += 16) {
    {
      const int r = tid >> 2;          // 0..63
      const int c = (tid & 3) * 4;     // 0,4,8,12
      const float4 a4 = *(const float4*)&A[(rowBase + r) * D_ + k0 + c];
      As[c + 0][r] = a4.x; As[c + 1][r] = a4.y;
      As[c + 2][r] = a4.z; As[c + 3][r] = a4.w;
      const int kk = tid >> 4;         // 0..15
      const int cc = (tid & 15) * 4;   // 0..60
      *(float4*)&Bs[kk][cc] = *(const float4*)&W[(k0 + kk) * U_ + colBase + cc];
    }
    __syncthreads();
#pragma unroll
    for (int k = 0; k < 16; ++k) {
      float av[4], bv[4];
      *(float4*)av = *(const float4*)&As[k][ty * 4];
      *(float4*)bv = *(const float4*)&Bs[k][tx * 4];
#pragma unroll
      for (int i = 0; i < 4; ++i)
#pragma unroll
        for (int j = 0; j < 4; ++j)
          acc[i][j] = fmaf(av[i], bv[j], acc[i][j]);
    }
    __syncthreads();
  }
#pragma unroll
  for (int i = 0; i < 4; ++i) {
    float4 o;
    o.x = fexp2(acc[i][0] * TWO_LOG2E_F);
    o.y = fexp2(acc[i][1] * TWO_LOG2E_F);
    o.z = fexp2(acc[i][2] * TWO_LOG2E_F);
    o.w = fexp2(acc[i][3] * TWO_LOG2E_F);
    *(float4*)&out[(rowBase + ty * 4 + i) * U_ + colBase + tx * 4] = o;
  }
}

// ---------------------------------------------------------------------------
// K2 (dominant): mu'[b,s,t] = sum_u (-2 nu_u) * rcp(fma(Ed[b,s,u], Ee[b,t,u], 1))
//   (= sum_u nu_u * tanh(ad+ae) minus the softmax-invariant constant sum(nu))
// Per element: 1 trans (rcp) + 2 VALU (fma) -- trans-pipe floor ~7 us.
// E->0 => tanh->-1 (rcp(1)=1); E->inf => rcp->0 => tanh->+1: robust.
// 32x32 (s,t) tile per block, 2x2 per thread (strided +16), u-chunks of 16.
// grid (8, 8, 8) = 512 blocks.
// ---------------------------------------------------------------------------
__global__ __launch_bounds__(256) void coatt_k2_mu(
    const float* __restrict__ nu, float* __restrict__ ws) {
  const float* __restrict__ ae = ws + AE_OFF;
  const float* __restrict__ ad = ws + AD_OFF;
  float* __restrict__ mu = ws + MU_OFF;
  const int b = blockIdx.z;
  const int sBase = blockIdx.y * 32;
  const int tBase = blockIdx.x * 32;
  __shared__ float ADs[32][20];  // pad 20: rows 80B (16B-aligned), conflict-free b128
  __shared__ float AEs[32][20];
  __shared__ float NUs[16];
  const int tid = threadIdx.x;
  const int tx = tid & 15;
  const int sy = tid >> 4;
  float acc00 = 0.f, acc01 = 0.f, acc10 = 0.f, acc11 = 0.f;
  for (int u0 = 0; u0 < U_; u0 += 16) {
    {
      const int r = (tid & 127) >> 2;  // 0..31
      const int c = (tid & 3) * 4;
      if (tid < 128)
        *(float4*)&ADs[r][c] = *(const float4*)&ad[(b * TD_ + sBase + r) * U_ + u0 + c];
      else
        *(float4*)&AEs[r][c] = *(const float4*)&ae[(b * TE_ + tBase + r) * U_ + u0 + c];
      if (tid < 4) {
        const float4 n4 = *(const float4*)&nu[u0 + tid * 4];
        NUs[tid * 4 + 0] = -2.0f * n4.x;
        NUs[tid * 4 + 1] = -2.0f * n4.y;
        NUs[tid * 4 + 2] = -2.0f * n4.z;
        NUs[tid * 4 + 3] = -2.0f * n4.w;
      }
    }
    __syncthreads();
    const float4* A0 = (const float4*)&ADs[sy][0];
    const float4* A1 = (const float4*)&ADs[sy + 16][0];
    const float4* E0 = (const float4*)&AEs[tx][0];
    const float4* E1 = (const float4*)&AEs[tx + 16][0];
    const float4* N4 = (const float4*)&NUs[0];
#pragma unroll
    for (int q = 0; q < 4; ++q) {
      float a0v[4], a1v[4], e0v[4], e1v[4], nv[4];
      *(float4*)a0v = A0[q];
      *(float4*)a1v = A1[q];
      *(float4*)e0v = E0[q];
      *(float4*)e1v = E1[q];
      *(float4*)nv  = N4[q];
#pragma unroll
      for (int u = 0; u < 4; ++u) {
        const float r00 = frcp(fmaf(a0v[u], e0v[u], 1.0f));
        const float r01 = frcp(fmaf(a0v[u], e1v[u], 1.0f));
        const float r10 = frcp(fmaf(a1v[u], e0v[u], 1.0f));
        const float r11 = frcp(fmaf(a1v[u], e1v[u], 1.0f));
        acc00 = fmaf(nv[u], r00, acc00);
        acc01 = fmaf(nv[u], r01, acc01);
        acc10 = fmaf(nv[u], r10, acc10);
        acc11 = fmaf(nv[u], r11, acc11);
      }
    }
    __syncthreads();
  }
  const int s0 = sBase + sy, s1 = s0 + 16;
  const int t0 = tBase + tx, t1 = t0 + 16;
  mu[(b * TD_ + s0) * TE_ + t0] = acc00;
  mu[(b * TD_ + s0) * TE_ + t1] = acc01;
  mu[(b * TD_ + s1) * TE_ + t0] = acc10;
  mu[(b * TD_ + s1) * TE_ + t1] = acc11;
}

// ---------------------------------------------------------------------------
// K3: per-(b,s) row softmax over te (in-place mu -> alphas) + row max out.
// One wave per row, 4 f32 per lane (float4), shuffle-butterfly reductions,
// zero barriers. grid 512 blocks x 256 threads (4 waves = 4 rows / block).
// ---------------------------------------------------------------------------
__global__ __launch_bounds__(256) void coatt_k3_softmax(float* __restrict__ ws) {
  float* __restrict__ mu = ws + MU_OFF;
  float* __restrict__ maxmu = ws + MAXMU_OFF;
  const int tid = threadIdx.x;
  const int wave = tid >> 6, lane = tid & 63;
  const int row = blockIdx.x * 4 + wave;  // b*TD + s
  float4 v = *(const float4*)&mu[row * TE_ + lane * 4];
  float m = fmaxf(fmaxf(v.x, v.y), fmaxf(v.z, v.w));
#pragma unroll
  for (int off = 32; off > 0; off >>= 1) m = fmaxf(m, __shfl_xor(m, off));
  float4 e;
  e.x = fexp2((v.x - m) * LOG2E_F);
  e.y = fexp2((v.y - m) * LOG2E_F);
  e.z = fexp2((v.z - m) * LOG2E_F);
  e.w = fexp2((v.w - m) * LOG2E_F);
  float s = (e.x + e.y) + (e.z + e.w);
#pragma unroll
  for (int off = 32; off > 0; off >>= 1) s += __shfl_xor(s, off);
  const float inv = frcp(s);
  e.x *= inv; e.y *= inv; e.z *= inv; e.w *= inv;
  *(float4*)&mu[row * TE_ + lane * 4] = e;
  if (lane == 0) maxmu[row] = m;
}

// ---------------------------------------------------------------------------
// K4: max_alphas = softmax_s(maxmu[b,:]) (recomputed per block, cheap);
//     h_hat[b,d] = sum_s de[b,s,d]*max_alphas[s].
// grid (8 dChunks, 8 b); each block covers 32 d, splits s 8 ways, LDS-reduces.
// ---------------------------------------------------------------------------
__global__ __launch_bounds__(256) void coatt_k4_hhat(
    const float* __restrict__ de, float* __restrict__ ws) {
  const float* __restrict__ maxmu = ws + MAXMU_OFF;
  float* __restrict__ hhat = ws + HH_OFF;
  const int b = blockIdx.y;
  const int dBase = blockIdx.x * 32;
  const int tid = threadIdx.x;
  __shared__ float red[256];
  __shared__ float malpha[256];
  const float v = maxmu[b * TD_ + tid];
  red[tid] = v;
  __syncthreads();
  for (int w = 128; w > 0; w >>= 1) {
    if (tid < w) red[tid] = fmaxf(red[tid], red[tid + w]);
    __syncthreads();
  }
  const float m = red[0];
  __syncthreads();
  const float e = fexp2((v - m) * LOG2E_F);
  red[tid] = e;
  __syncthreads();
  for (int w = 128; w > 0; w >>= 1) {
    if (tid < w) red[tid] += red[tid + w];
    __syncthreads();
  }
  malpha[tid] = e * frcp(red[0]);
  __syncthreads();
  const int dl = tid & 31, sg = tid >> 5;
  float acc = 0.f;
  for (int s = sg * 32; s < sg * 32 + 32; ++s)
    acc = fmaf(de[(b * TD_ + s) * D_ + dBase + dl], malpha[s], acc);
  red[tid] = acc;
  __syncthreads();
  if (tid < 32) {
    float t = red[tid];
#pragma unroll
    for (int g = 1; g < 8; ++g) t += red[g * 32 + tid];
    hhat[b * D_ + dBase + tid] = t;
  }
}

// ---------------------------------------------------------------------------
// K5: sum_en = alphas @ en (per-b 256x256 @ 256x256), fused with output concat:
//     out = [de | sum_en | de*sum_en | de*h_hat].  32x32 tile, 2x2/thread.
// grid (8 eTiles, 8 sTiles, 8 b) = 512 blocks.
// ---------------------------------------------------------------------------
__global__ __launch_bounds__(256) void coatt_k5_out(
    const float* __restrict__ en, const float* __restrict__ de,
    const float* __restrict__ ws, float* __restrict__ out) {
  const float* __restrict__ alphas = ws + MU_OFF;  // (B*TD, TE)
  const float* __restrict__ hhat = ws + HH_OFF;
  const int b = blockIdx.z;
  const int sBase = blockIdx.y * 32;
  const int eBase = blockIdx.x * 32;
  __shared__ float As[16][36];  // As[t][s] (alphas^T chunk), pad 36
  __shared__ float Bs[16][36];  // Bs[t][e]
  const int tid = threadIdx.x;
  const int tx = tid & 15, sy = tid >> 4;
  float acc[2][2] = {};
  for (int k0 = 0; k0 < TE_; k0 += 16) {
    if (tid < 128) {
      const int r = tid >> 2, c = (tid & 3) * 4;  // r: s-local, c: t-offset
      const float4 a4 = *(const float4*)&alphas[(b * TD_ + sBase + r) * TE_ + k0 + c];
      As[c + 0][r] = a4.x; As[c + 1][r] = a4.y;
      As[c + 2][r] = a4.z; As[c + 3][r] = a4.w;
    } else {
      const int id = tid & 127;
      const int kk = id >> 3, cc = (id & 7) * 4;  // kk: t-local, cc: e-offset
      *(float4*)&Bs[kk][cc] = *(const float4*)&en[(b * TE_ + k0 + kk) * D_ + eBase + cc];
    }
    __syncthreads();
#pragma unroll
    for (int k = 0; k < 16; ++k) {
      const float2 a2 = *(const float2*)&As[k][sy * 2];
      const float2 b2 = *(const float2*)&Bs[k][tx * 2];
      acc[0][0] = fmaf(a2.x, b2.x, acc[0][0]);
      acc[0][1] = fmaf(a2.x, b2.y, acc[0][1]);
      acc[1][0] = fmaf(a2.y, b2.x, acc[1][0]);
      acc[1][1] = fmaf(a2.y, b2.y, acc[1][1]);
    }
    __syncthreads();
  }
  const int e0 = eBase + tx * 2;
  const float2 hh = *(const float2*)&hhat[b * D_ + e0];
#pragma unroll
  for (int i = 0; i < 2; ++i) {
    const int s = sBase + sy * 2 + i;
    const float2 d2 = *(const float2*)&de[(b * TD_ + s) * D_ + e0];
    float* o = out + (size_t)(b * TD_ + s) * (4 * D_);
    float2 se; se.x = acc[i][0]; se.y = acc[i][1];
    *(float2*)&o[e0] = d2;
    *(float2*)&o[D_ + e0] = se;
    float2 p; p.x = d2.x * se.x; p.y = d2.y * se.y;
    *(float2*)&o[2 * D_ + e0] = p;
    float2 q; q.x = d2.x * hh.x; q.y = d2.y * hh.y;
    *(float2*)&o[3 * D_ + e0] = q;
  }
}

extern "C" void kernel_launch(void* const* d_in, const int* in_sizes, int n_in,
                              void* d_out, int out_size, void* d_ws, size_t ws_size,
                              hipStream_t stream) {
  (void)in_sizes; (void)n_in; (void)out_size; (void)ws_size;
  const float* en   = (const float*)d_in[0];
  const float* de   = (const float*)d_in[1];
  const float* w_en = (const float*)d_in[2];
  const float* w_de = (const float*)d_in[3];
  const float* nu   = (const float*)d_in[4];
  float* out = (float*)d_out;
  float* ws  = (float*)d_ws;

  coatt_k1_proj<<<dim3(4, 32, 2), 256, 0, stream>>>(en, de, w_en, w_de, ws);
  coatt_k2_mu<<<dim3(8, 8, 8), 256, 0, stream>>>(nu, ws);
  coatt_k3_softmax<<<dim3(512), 256, 0, stream>>>(ws);
  coatt_k4_hhat<<<dim3(8, 8), 256, 0, stream>>>(de, ws);
  coatt_k5_out<<<dim3(8, 8, 8), 256, 0, stream>>>(en, de, ws, out);
}